// Round 8
// baseline (289.537 us; speedup 1.0000x reference)
//
#include <hip/hip_runtime.h>
#include <hip/hip_bf16.h>
#include <math.h>

#define B_ 2
#define T_ 2048
#define C_ 1024
#define H_ 16
#define G_ 4
#define DQK_ 64
#define DV_ 128
#define NQKV 1792   // H*DQK + G*DQK + G*DV
#define KS2 2048    // compact split storage: [hi | lo]
// Logical GEMM K = 3072 tiles 0..95: s0=hi·hi (0..31), s1=lo·hi (32..63),
// s2=hi·lo (64..95). Column remap: ktA = kt<64?kt:kt-64; ktB = kt<32?kt:kt-32.
// Operand rows chunk-XOR-swizzled: chunk c of row r at phys chunk c^((r>>1)&3).

typedef __attribute__((ext_vector_type(8))) short short8;
typedef __attribute__((ext_vector_type(4))) float f32x4;
typedef unsigned short ushort_t;

__device__ inline ushort_t f2bf(float f) {
  union { float f; unsigned int u; } v; v.f = f;
  unsigned int r = (v.u + 0x7FFFu + ((v.u >> 16) & 1u)) >> 16;  // RNE
  return (ushort_t)r;
}
__device__ inline float bf2f(ushort_t h) {
  union { unsigned int u; float f; } v; v.u = ((unsigned int)h) << 16;
  return v.f;
}

#define GLD_LDS16(g, l)                                              \
  __builtin_amdgcn_global_load_lds(                                  \
      (const __attribute__((address_space(1))) void*)(g),            \
      (__attribute__((address_space(3))) void*)(l), 16, 0, 0)

// ---------------------------------------------------------------------------
// Kernel 0a: split-cast x -> xb[4096][2048] bf16 = [x_hi | x_lo], swizzled.
// ---------------------------------------------------------------------------
__global__ __launch_bounds__(256) void cast_x(
    const float* __restrict__ x, ushort_t* __restrict__ xb) {
  int idx = blockIdx.x * 256 + threadIdx.x;   // 524288
  int m = idx >> 7;
  int c8 = idx & 127;
  const float* src = &x[(size_t)m * 1024 + c8 * 8];
  float4 v0 = *(const float4*)&src[0];
  float4 v1 = *(const float4*)&src[4];
  float f[8] = {v0.x, v0.y, v0.z, v0.w, v1.x, v1.y, v1.z, v1.w};
  short8 hv, lv;
#pragma unroll
  for (int c = 0; c < 8; c++) {
    ushort_t h = f2bf(f[c]);
    hv[c] = (short)h;
    lv[c] = (short)f2bf(f[c] - bf2f(h));
  }
  int key = (m >> 1) & 3;
  int phys = (c8 & ~3) * 8 + ((c8 & 3) ^ key) * 8;
  ushort_t* row = xb + (size_t)m * KS2;
  *(short8*)&row[phys] = hv;
  *(short8*)&row[1024 + phys] = lv;
}

// ---------------------------------------------------------------------------
// Kernel 0b: transpose+split-cast W -> wt[1792][2048] bf16, swizzled.
// ---------------------------------------------------------------------------
__global__ __launch_bounds__(256) void cast_w(
    const float* __restrict__ Wq, const float* __restrict__ Wk,
    const float* __restrict__ Wv, ushort_t* __restrict__ wt) {
  __shared__ float tile[64][65];
  const int n0 = blockIdx.x * 64;
  const int k0 = blockIdx.y * 64;
  const int tid = threadIdx.x;

  const float* Wp; int ldw, noff;
  if (n0 < 1024)      { Wp = Wq; ldw = 1024; noff = n0; }
  else if (n0 < 1280) { Wp = Wk; ldw = 256;  noff = n0 - 1024; }
  else                { Wp = Wv; ldw = 512;  noff = n0 - 1280; }

#pragma unroll
  for (int it = 0; it < 4; it++) {
    int fi = it * 256 + tid;
    int kk = fi >> 4;
    int nc = (fi & 15) * 4;
    float4 v = *(const float4*)&Wp[(size_t)(k0 + kk) * ldw + noff + nc];
    tile[nc + 0][kk] = v.x; tile[nc + 1][kk] = v.y;
    tile[nc + 2][kk] = v.z; tile[nc + 3][kk] = v.w;
  }
  __syncthreads();
  int nn = tid >> 2, seg = tid & 3;
  int n = n0 + nn;
  int key = (n >> 1) & 3;
  ushort_t* row = wt + (size_t)n * KS2;
#pragma unroll
  for (int j = 0; j < 2; j++) {
    short8 hv, lv;
#pragma unroll
    for (int u = 0; u < 8; u++) {
      float f = tile[nn][seg * 16 + j * 8 + u];
      ushort_t h = f2bf(f);
      hv[u] = (short)h;
      lv[u] = (short)f2bf(f - bf2f(h));
    }
    int c8 = (k0 >> 3) + seg * 2 + j;
    int phys = (c8 & ~3) * 8 + ((c8 & 3) ^ key) * 8;
    *(short8*)&row[phys] = hv;
    *(short8*)&row[1024 + phys] = lv;
  }
}

// ---------------------------------------------------------------------------
// Kernel 0c: cast Wproj[128][1024] -> bf16 B-fragment order.
// wpf offset: ((n>>7)*4 + (k>>5))*8 + ((n>>4)&7))*512 + (((k>>3)&3)*16+(n&15))*8 + (k&7)
// ---------------------------------------------------------------------------
__global__ __launch_bounds__(256) void cast_wp(
    const float* __restrict__ Wp, ushort_t* __restrict__ wpf) {
  int idx = blockIdx.x * 256 + threadIdx.x;   // 16384
  int n = idx & 1023;
  int kc = idx >> 10;                          // 0..15 (chunk of 8 k's)
  short8 v;
#pragma unroll
  for (int j = 0; j < 8; j++)
    v[j] = (short)f2bf(Wp[(size_t)(kc * 8 + j) * 1024 + n]);
  size_t off = (((size_t)(n >> 7) * 4 + (kc >> 2)) * 8 + ((n >> 4) & 7)) * 512 +
               ((kc & 3) * 16 + (n & 15)) * 8;
  *(short8*)&wpf[off] = v;
}

// ---------------------------------------------------------------------------
// Kernel 1: bf16-MFMA QKV GEMM.  2-barrier single-buffer K-loop (proven
// fastest structure for this shape) + conflict-free swizzled LDS.
// ---------------------------------------------------------------------------
__global__ __launch_bounds__(256) void gemm_qkv_mfma(
    const ushort_t* __restrict__ xb, const ushort_t* __restrict__ wt,
    float* __restrict__ qkv) {
  __shared__ ushort_t At[128 * 32];
  __shared__ ushort_t Bt[128 * 32];
  const int tid = threadIdx.x;
  const int wave = tid >> 6, lane = tid & 63;
  const int quad = lane >> 4, l16 = lane & 15;
  const int m0 = blockIdx.y * 128, n0 = blockIdx.x * 128;
  const int wm = (wave & 1) * 64, wn = (wave >> 1) * 64;
  const int physq = (quad ^ ((l16 >> 1) & 3)) * 8;   // de-swizzle read column

  f32x4 acc[4][4];
#pragma unroll
  for (int i = 0; i < 4; i++)
#pragma unroll
    for (int j = 0; j < 4; j++) acc[i][j] = (f32x4){0.f, 0.f, 0.f, 0.f};

  const int rA = wave * 32 + (lane >> 2);
  const int cA = (lane & 3) * 8;
  const ushort_t* gA = xb + (size_t)(m0 + rA) * KS2 + cA;
  const ushort_t* gB = wt + (size_t)(n0 + rA) * KS2 + cA;
  ushort_t* lA0 = At + (size_t)(wave * 32) * 32;
  ushort_t* lA1 = At + (size_t)(wave * 32 + 16) * 32;
  ushort_t* lB0 = Bt + (size_t)(wave * 32) * 32;
  ushort_t* lB1 = Bt + (size_t)(wave * 32 + 16) * 32;

  for (int kt = 0; kt < 96; kt++) {
    const int ca = (kt < 64 ? kt : kt - 64) * 32;
    const int cb = (kt < 32 ? kt : kt - 32) * 32;
    __syncthreads();
    GLD_LDS16(gA + ca, lA0);
    GLD_LDS16(gA + ca + 16 * KS2, lA1);
    GLD_LDS16(gB + cb, lB0);
    GLD_LDS16(gB + cb + 16 * KS2, lB1);
    __syncthreads();

    short8 af[4], bf[4];
#pragma unroll
    for (int i = 0; i < 4; i++)
      af[i] = *(const short8*)&At[(wm + 16 * i + l16) * 32 + physq];
#pragma unroll
    for (int j = 0; j < 4; j++)
      bf[j] = *(const short8*)&Bt[(wn + 16 * j + l16) * 32 + physq];
#pragma unroll
    for (int i = 0; i < 4; i++)
#pragma unroll
      for (int j = 0; j < 4; j++)
        acc[i][j] = __builtin_amdgcn_mfma_f32_16x16x32_bf16(
            af[i], bf[j], acc[i][j], 0, 0, 0);
  }

#pragma unroll
  for (int i = 0; i < 4; i++) {
    int m = m0 + wm + 16 * i + quad * 4;
#pragma unroll
    for (int j = 0; j < 4; j++) {
      int n = n0 + wn + 16 * j + l16;
#pragma unroll
      for (int r = 0; r < 4; r++)
        qkv[(size_t)(m + r) * NQKV + n] = acc[i][j][r];
    }
  }
}

// ---------------------------------------------------------------------------
// Kernel 2: RoPE + qk-norm -> unit-norm bf16 q,k in MFMA-fragment layouts.
// ---------------------------------------------------------------------------
__global__ __launch_bounds__(256) void rope_norm(
    const float* __restrict__ qkv,
    ushort_t* __restrict__ qf, ushort_t* __restrict__ kf) {
  const int NQ = B_ * T_ * H_;
  int vec = blockIdx.x * 4 + (threadIdx.x >> 6);
  int d = threadIdx.x & 63;

  size_t src; int t, b, isq; ushort_t* dstbase;
  if (vec < NQ) {
    int h = vec % H_; int bt = vec / H_;
    t = bt % T_; b = bt / T_;
    src = (size_t)bt * NQKV + h * 64 + d;
    dstbase = qf + (size_t)(b * 16 + h) * 131072;
    isq = 1;
  } else {
    int vk = vec - NQ;
    int g = vk % G_; int bt = vk / G_;
    t = bt % T_; b = bt / T_;
    src = (size_t)bt * NQKV + 1024 + g * 64 + d;
    dstbase = kf + (size_t)(b * 4 + g) * 131072;
    isq = 0;
  }
  float val = qkv[src];
  int i = d & 31;
  float inv = exp2f(-(float)i * 0.4152410118074239f);  // log2(10000)/32
  float ang = (float)t * inv;
  float sn, cs;
  __sincosf(ang, &sn, &cs);
  float partner = __shfl(val, d ^ 32, 64);
  float r = (d < 32) ? (val * cs - partner * sn) : (val * cs + partner * sn);
  float ss = r * r;
#pragma unroll
  for (int off = 32; off; off >>= 1) ss += __shfl_xor(ss, off, 64);
  r *= 1.0f / (sqrtf(ss) + 1e-6f);

  int kt = t >> 6, tt = t & 63;
  int l16v = tt & 15;
  int ks = d >> 5, quad = (d >> 3) & 3, j = d & 7;
  size_t off2;
  if (isq) {
    int wavei = tt >> 4;
    off2 = ((size_t)(kt * 8 + wavei * 2 + ks) * 4 + quad) * 128 + l16v * 8 + j;
  } else {
    int nt = tt >> 4;
    off2 = ((size_t)(kt * 8 + ks * 4 + nt) * 4 + quad) * 128 + l16v * 8 + j;
  }
  dstbase[off2] = f2bf(r);
}

// ---------------------------------------------------------------------------
// Kernel 2b: V scatter + bf16 cast into PV B-fragment layout.
// ---------------------------------------------------------------------------
__global__ __launch_bounds__(256) void vscatter(
    const float* __restrict__ qkv, ushort_t* __restrict__ vf) {
  int idx = blockIdx.x * 256 + threadIdx.x;   // 2,097,152
  int dv = idx & 127;
  int t = (idx >> 7) & 2047;
  int g = (idx >> 18) & 3;
  int b = idx >> 20;
  size_t src = (size_t)(b * T_ + t) * NQKV + 1280 + g * 128 + dv;
  float v = qkv[src];
  int kt = t >> 6, ks = (t >> 5) & 1, quad = (t >> 3) & 3, j = t & 7;
  int nv = dv >> 4, l16v = dv & 15;
  size_t off = ((size_t)(kt * 16 + ks * 8 + nv) * 4 + quad) * 128 + l16v * 8 + j;
  vf[(size_t)(b * 4 + g) * 262144 + off] = f2bf(v);
}

// ---------------------------------------------------------------------------
// Kernel 3: bf16-MFMA causal flash attention, fixed-max softmax (m = gsc).
// BARRIER-FREE K-loop: K/V fragments loaded straight to VGPRs (operands are
// pre-laid-out in fragment order); P round-trips per-wave LDS; l via
// ones-column MFMA.  One barrier total (Vones init).
// ---------------------------------------------------------------------------
__global__ __launch_bounds__(256, 2) void attn(
    const ushort_t* __restrict__ qf, const ushort_t* __restrict__ kf,
    const ushort_t* __restrict__ vf, const float* __restrict__ lobo,
    const float* __restrict__ qknf, float* __restrict__ y) {
  const int f = blockIdx.x;
  const int b = f >> 9;
  const int h = (f >> 5) & 15;
  const int qt = ((f & 31) + 8 * (f >> 8)) & 31;   // spread qt across CUs
  const int g = h >> 2;

  __shared__ ushort_t Vones[512];
  __shared__ ushort_t Ps[64 * 68];

  const int tid = threadIdx.x;
  const int wave = tid >> 6, lane = tid & 63;
  const int quad = lane >> 4, l16 = lane & 15;

  if (tid < 64) {
    ushort_t vv = ((tid & 15) == 0) ? (ushort_t)0x3F80 : (ushort_t)0;
#pragma unroll
    for (int u = 0; u < 8; u++) Vones[tid * 8 + u] = vv;
  }
  __syncthreads();   // only barrier: Vones visible to all waves

  const ushort_t* qb =
      qf + ((size_t)((b * 16 + h) * 32 + qt) * 8 + wave * 2) * 512;
  short8 aq0 = *(const short8*)&qb[lane * 8];
  short8 aq1 = *(const short8*)&qb[512 + lane * 8];
  short8 bones = *(const short8*)&Vones[lane * 8];

  f32x4 o[9];
#pragma unroll
  for (int nv = 0; nv < 9; nv++) o[nv] = (f32x4){0.f, 0.f, 0.f, 0.f};

  const float gsc = qknf[0];
  const float sinkp = __expf(lobo[h] - gsc);

  const ushort_t* kt0 = kf + (size_t)(b * 4 + g) * 131072 + lane * 8;
  const ushort_t* vt0 = vf + (size_t)(b * 4 + g) * 262144 + lane * 8;

  for (int kt = 0; kt <= qt; kt++) {
    const ushort_t* kg = kt0 + (size_t)kt * 4096;
    const ushort_t* vg = vt0 + (size_t)kt * 8192;
    short8 kfr[8];
#pragma unroll
    for (int u = 0; u < 8; u++) kfr[u] = *(const short8*)&kg[u * 512];
    short8 vfr[16];
#pragma unroll
    for (int u = 0; u < 16; u++) vfr[u] = *(const short8*)&vg[u * 512];

    f32x4 s[4];
#pragma unroll
    for (int nt = 0; nt < 4; nt++) s[nt] = (f32x4){0.f, 0.f, 0.f, 0.f};
#pragma unroll
    for (int nt = 0; nt < 4; nt++)
      s[nt] = __builtin_amdgcn_mfma_f32_16x16x32_bf16(aq0, kfr[nt], s[nt], 0, 0, 0);
#pragma unroll
    for (int nt = 0; nt < 4; nt++)
      s[nt] = __builtin_amdgcn_mfma_f32_16x16x32_bf16(aq1, kfr[4 + nt], s[nt], 0, 0, 0);

    // fixed-max softmax: p = exp(gsc*(s-1)); causal mask on diagonal tile
    const bool diag = (kt == qt);
#pragma unroll
    for (int nt = 0; nt < 4; nt++)
#pragma unroll
      for (int r = 0; r < 4; r++) {
        float p = __expf((s[nt][r] - 1.0f) * gsc);
        if (diag && (nt * 16 + l16) > (wave * 16 + quad * 4 + r)) p = 0.f;
        Ps[(wave * 16 + quad * 4 + r) * 68 + nt * 16 + l16] = f2bf(p);
      }

    short8 ap0 = *(const short8*)&Ps[(wave * 16 + l16) * 68 + quad * 8];
    short8 ap1 = *(const short8*)&Ps[(wave * 16 + l16) * 68 + 32 + quad * 8];
#pragma unroll
    for (int nv = 0; nv < 8; nv++)
      o[nv] = __builtin_amdgcn_mfma_f32_16x16x32_bf16(ap0, vfr[nv], o[nv], 0, 0, 0);
    o[8] = __builtin_amdgcn_mfma_f32_16x16x32_bf16(ap0, bones, o[8], 0, 0, 0);
    o[8] = __builtin_amdgcn_mfma_f32_16x16x32_bf16(ap1, bones, o[8], 0, 0, 0);
#pragma unroll
    for (int nv = 0; nv < 8; nv++)
      o[nv] = __builtin_amdgcn_mfma_f32_16x16x32_bf16(ap1, vfr[8 + nv], o[nv], 0, 0, 0);
  }

  // epilogue: l = sink + mfma row-sum (col 0 of o[8]); normalize; head-sum
#pragma unroll
  for (int r = 0; r < 4; r++) {
    float lm = __shfl(o[8][r], lane & 48, 64);
    float invl = 1.0f / (lm + sinkp);
    size_t row = (size_t)b * T_ + qt * 64 + wave * 16 + quad * 4 + r;
#pragma unroll
    for (int nv = 0; nv < 8; nv++)
      atomicAdd(&y[row * 128 + nv * 16 + l16], o[nv][r] * invl);
  }
}

// ---------------------------------------------------------------------------
// Kernel 4: out = y[4096][128] @ Wproj[128][1024] via bf16 MFMA.
// Grid (8 n-tiles, 32 m-tiles); y staged f32->bf16 LDS; Wproj pre-fragmented.
// ---------------------------------------------------------------------------
__global__ __launch_bounds__(256) void out_proj(
    const float* __restrict__ y, const ushort_t* __restrict__ wpf,
    float* __restrict__ out) {
  __shared__ ushort_t yl[128 * 136];   // stride 136 -> <=2-way banks
  const int tid = threadIdx.x;
  const int wave = tid >> 6, lane = tid & 63;
  const int quad = lane >> 4, l16 = lane & 15;
  const int n0 = blockIdx.x * 128, m0 = blockIdx.y * 128;
  const int wm = (wave & 1) * 64, wn = (wave >> 1) * 64;

#pragma unroll
  for (int it = 0; it < 8; it++) {
    int p = it * 256 + tid;            // 2048 (row, chunk) pairs
    int row = p >> 4, c8 = p & 15;
    const float* src = &y[(size_t)(m0 + row) * 128 + c8 * 8];
    float4 v0 = *(const float4*)&src[0];
    float4 v1 = *(const float4*)&src[4];
    float fv[8] = {v0.x, v0.y, v0.z, v0.w, v1.x, v1.y, v1.z, v1.w};
    short8 hv;
#pragma unroll
    for (int c = 0; c < 8; c++) hv[c] = (short)f2bf(fv[c]);
    *(short8*)&yl[row * 136 + c8 * 8] = hv;
  }
  __syncthreads();

  f32x4 acc[4][4];
#pragma unroll
  for (int i = 0; i < 4; i++)
#pragma unroll
    for (int j = 0; j < 4; j++) acc[i][j] = (f32x4){0.f, 0.f, 0.f, 0.f};

#pragma unroll
  for (int ks = 0; ks < 4; ks++) {
    short8 af[4], bfr[4];
#pragma unroll
    for (int i = 0; i < 4; i++)
      af[i] = *(const short8*)&yl[(wm + 16 * i + l16) * 136 + (ks * 4 + quad) * 8];
    const ushort_t* wb = wpf + (((size_t)(n0 >> 7) * 4 + ks) * 8) * 512;
#pragma unroll
    for (int j = 0; j < 4; j++)
      bfr[j] = *(const short8*)&wb[((size_t)((wn >> 4) + j)) * 512 + lane * 8];
#pragma unroll
    for (int i = 0; i < 4; i++)
#pragma unroll
      for (int j = 0; j < 4; j++)
        acc[i][j] = __builtin_amdgcn_mfma_f32_16x16x32_bf16(
            af[i], bfr[j], acc[i][j], 0, 0, 0);
  }

#pragma unroll
  for (int i = 0; i < 4; i++) {
    int m = m0 + wm + 16 * i + quad * 4;
#pragma unroll
    for (int j = 0; j < 4; j++) {
      int n = n0 + wn + 16 * j + l16;
#pragma unroll
      for (int r = 0; r < 4; r++)
        out[(size_t)(m + r) * 1024 + n] = acc[i][j][r];
    }
  }
}

// ---------------------------------------------------------------------------
extern "C" void kernel_launch(void* const* d_in, const int* in_sizes, int n_in,
                              void* d_out, int out_size, void* d_ws, size_t ws_size,
                              hipStream_t stream) {
  const float* x     = (const float*)d_in[0];
  const float* Wq    = (const float*)d_in[2];
  const float* Wk    = (const float*)d_in[3];
  const float* Wv    = (const float*)d_in[4];
  const float* Wproj = (const float*)d_in[5];
  const float* lobo  = (const float*)d_in[6];
  const float* qknf  = (const float*)d_in[7];
  float* out = (float*)d_out;

  // ws: [qkv f32 29.4MB | xb 16.8MB | wt 7.3MB | wpf 0.25MB]; qf/kf/vf/y alias xb.
  float* qkv = (float*)d_ws;                                    // 7,340,032 f32
  ushort_t* xb = (ushort_t*)(qkv + (size_t)B_ * T_ * NQKV);     // 8,388,608 bf16
  ushort_t* wt = xb + (size_t)B_ * T_ * KS2;                    // 3,670,016 bf16
  ushort_t* wpf = wt + (size_t)NQKV * KS2;                      //   131,072 bf16
  ushort_t* qf = xb;                                            // 4,194,304 bf16
  ushort_t* kf = qf + (size_t)B_ * H_ * T_ * 64;                // 1,048,576 bf16
  ushort_t* vf = kf + (size_t)B_ * G_ * T_ * 64;                // 2,097,152 bf16
  float* y = (float*)(vf + (size_t)B_ * G_ * T_ * 128);         //   524,288 f32

  cast_x<<<(B_ * T_ * 128) / 256, 256, 0, stream>>>(x, xb);
  dim3 gw(NQKV / 64, C_ / 64);
  cast_w<<<gw, 256, 0, stream>>>(Wq, Wk, Wv, wt);
  cast_wp<<<64, 256, 0, stream>>>(Wproj, wpf);

  dim3 gg(NQKV / 128, (B_ * T_) / 128);
  gemm_qkv_mfma<<<gg, 256, 0, stream>>>(xb, wt, qkv);

  int nvec = B_ * T_ * H_ + B_ * T_ * G_;   // 81920
  rope_norm<<<nvec / 4, 256, 0, stream>>>(qkv, qf, kf);

  vscatter<<<(B_ * G_ * T_ * DV_) / 256, 256, 0, stream>>>(qkv, vf);

  (void)hipMemsetAsync(y, 0, (size_t)B_ * T_ * 128 * sizeof(float), stream);

  attn<<<B_ * H_ * (T_ / 64), 256, 0, stream>>>(qf, kf, vf, lobo, qknf, y);

  dim3 go(8, 32);
  out_proj<<<go, 256, 0, stream>>>(y, wpf, out);
}

// Round 9
// 279.647 us; speedup vs baseline: 1.0354x; 1.0354x over previous
//
#include <hip/hip_runtime.h>
#include <hip/hip_bf16.h>
#include <math.h>

#define B_ 2
#define T_ 2048
#define C_ 1024
#define H_ 16
#define G_ 4
#define DQK_ 64
#define DV_ 128
#define NQKV 1792   // H*DQK + G*DQK + G*DV
#define KS2 2048    // compact split storage: [hi | lo]
// Logical GEMM K = 3072 tiles 0..95: s0=hi·hi (0..31), s1=lo·hi (32..63),
// s2=hi·lo (64..95). Column remap: ktA = kt<64?kt:kt-64; ktB = kt<32?kt:kt-32.
// Operand rows chunk-XOR-swizzled: chunk c of row r at phys chunk c^((r>>1)&3).

typedef __attribute__((ext_vector_type(8))) short short8;
typedef __attribute__((ext_vector_type(4))) float f32x4;
typedef unsigned short ushort_t;

__device__ inline ushort_t f2bf(float f) {
  union { float f; unsigned int u; } v; v.f = f;
  unsigned int r = (v.u + 0x7FFFu + ((v.u >> 16) & 1u)) >> 16;  // RNE
  return (ushort_t)r;
}
__device__ inline float bf2f(ushort_t h) {
  union { unsigned int u; float f; } v; v.u = ((unsigned int)h) << 16;
  return v.f;
}

#define GLD_LDS16(g, l)                                              \
  __builtin_amdgcn_global_load_lds(                                  \
      (const __attribute__((address_space(1))) void*)(g),            \
      (__attribute__((address_space(3))) void*)(l), 16, 0, 0)

// ---------------------------------------------------------------------------
// Kernel 0a: split-cast x -> xb[4096][2048] bf16 = [x_hi | x_lo], swizzled.
// ---------------------------------------------------------------------------
__global__ __launch_bounds__(256) void cast_x(
    const float* __restrict__ x, ushort_t* __restrict__ xb) {
  int idx = blockIdx.x * 256 + threadIdx.x;   // 524288
  int m = idx >> 7;
  int c8 = idx & 127;
  const float* src = &x[(size_t)m * 1024 + c8 * 8];
  float4 v0 = *(const float4*)&src[0];
  float4 v1 = *(const float4*)&src[4];
  float f[8] = {v0.x, v0.y, v0.z, v0.w, v1.x, v1.y, v1.z, v1.w};
  short8 hv, lv;
#pragma unroll
  for (int c = 0; c < 8; c++) {
    ushort_t h = f2bf(f[c]);
    hv[c] = (short)h;
    lv[c] = (short)f2bf(f[c] - bf2f(h));
  }
  int key = (m >> 1) & 3;
  int phys = (c8 & ~3) * 8 + ((c8 & 3) ^ key) * 8;
  ushort_t* row = xb + (size_t)m * KS2;
  *(short8*)&row[phys] = hv;
  *(short8*)&row[1024 + phys] = lv;
}

// ---------------------------------------------------------------------------
// Kernel 0b: transpose+split-cast W -> wt[1792][2048] bf16, swizzled.
// ---------------------------------------------------------------------------
__global__ __launch_bounds__(256) void cast_w(
    const float* __restrict__ Wq, const float* __restrict__ Wk,
    const float* __restrict__ Wv, ushort_t* __restrict__ wt) {
  __shared__ float tile[64][65];
  const int n0 = blockIdx.x * 64;
  const int k0 = blockIdx.y * 64;
  const int tid = threadIdx.x;

  const float* Wp; int ldw, noff;
  if (n0 < 1024)      { Wp = Wq; ldw = 1024; noff = n0; }
  else if (n0 < 1280) { Wp = Wk; ldw = 256;  noff = n0 - 1024; }
  else                { Wp = Wv; ldw = 512;  noff = n0 - 1280; }

#pragma unroll
  for (int it = 0; it < 4; it++) {
    int fi = it * 256 + tid;
    int kk = fi >> 4;
    int nc = (fi & 15) * 4;
    float4 v = *(const float4*)&Wp[(size_t)(k0 + kk) * ldw + noff + nc];
    tile[nc + 0][kk] = v.x; tile[nc + 1][kk] = v.y;
    tile[nc + 2][kk] = v.z; tile[nc + 3][kk] = v.w;
  }
  __syncthreads();
  int nn = tid >> 2, seg = tid & 3;
  int n = n0 + nn;
  int key = (n >> 1) & 3;
  ushort_t* row = wt + (size_t)n * KS2;
#pragma unroll
  for (int j = 0; j < 2; j++) {
    short8 hv, lv;
#pragma unroll
    for (int u = 0; u < 8; u++) {
      float f = tile[nn][seg * 16 + j * 8 + u];
      ushort_t h = f2bf(f);
      hv[u] = (short)h;
      lv[u] = (short)f2bf(f - bf2f(h));
    }
    int c8 = (k0 >> 3) + seg * 2 + j;
    int phys = (c8 & ~3) * 8 + ((c8 & 3) ^ key) * 8;
    *(short8*)&row[phys] = hv;
    *(short8*)&row[1024 + phys] = lv;
  }
}

// ---------------------------------------------------------------------------
// Kernel 0c: cast Wproj[128][1024] -> bf16 B-fragment order.
// ---------------------------------------------------------------------------
__global__ __launch_bounds__(256) void cast_wp(
    const float* __restrict__ Wp, ushort_t* __restrict__ wpf) {
  int idx = blockIdx.x * 256 + threadIdx.x;   // 16384
  int n = idx & 1023;
  int kc = idx >> 10;                          // 0..15 (chunk of 8 k's)
  short8 v;
#pragma unroll
  for (int j = 0; j < 8; j++)
    v[j] = (short)f2bf(Wp[(size_t)(kc * 8 + j) * 1024 + n]);
  size_t off = (((size_t)(n >> 7) * 4 + (kc >> 2)) * 8 + ((n >> 4) & 7)) * 512 +
               ((kc & 3) * 16 + (n & 15)) * 8;
  *(short8*)&wpf[off] = v;
}

// ---------------------------------------------------------------------------
// Kernel 1: bf16-MFMA QKV GEMM.  2-barrier single-buffer K-loop +
// conflict-free swizzled LDS (proven best so far).
// ---------------------------------------------------------------------------
__global__ __launch_bounds__(256) void gemm_qkv_mfma(
    const ushort_t* __restrict__ xb, const ushort_t* __restrict__ wt,
    float* __restrict__ qkv) {
  __shared__ ushort_t At[128 * 32];
  __shared__ ushort_t Bt[128 * 32];
  const int tid = threadIdx.x;
  const int wave = tid >> 6, lane = tid & 63;
  const int quad = lane >> 4, l16 = lane & 15;
  const int m0 = blockIdx.y * 128, n0 = blockIdx.x * 128;
  const int wm = (wave & 1) * 64, wn = (wave >> 1) * 64;
  const int physq = (quad ^ ((l16 >> 1) & 3)) * 8;   // de-swizzle read column

  f32x4 acc[4][4];
#pragma unroll
  for (int i = 0; i < 4; i++)
#pragma unroll
    for (int j = 0; j < 4; j++) acc[i][j] = (f32x4){0.f, 0.f, 0.f, 0.f};

  const int rA = wave * 32 + (lane >> 2);
  const int cA = (lane & 3) * 8;
  const ushort_t* gA = xb + (size_t)(m0 + rA) * KS2 + cA;
  const ushort_t* gB = wt + (size_t)(n0 + rA) * KS2 + cA;
  ushort_t* lA0 = At + (size_t)(wave * 32) * 32;
  ushort_t* lA1 = At + (size_t)(wave * 32 + 16) * 32;
  ushort_t* lB0 = Bt + (size_t)(wave * 32) * 32;
  ushort_t* lB1 = Bt + (size_t)(wave * 32 + 16) * 32;

  for (int kt = 0; kt < 96; kt++) {
    const int ca = (kt < 64 ? kt : kt - 64) * 32;
    const int cb = (kt < 32 ? kt : kt - 32) * 32;
    __syncthreads();
    GLD_LDS16(gA + ca, lA0);
    GLD_LDS16(gA + ca + 16 * KS2, lA1);
    GLD_LDS16(gB + cb, lB0);
    GLD_LDS16(gB + cb + 16 * KS2, lB1);
    __syncthreads();

    short8 af[4], bf[4];
#pragma unroll
    for (int i = 0; i < 4; i++)
      af[i] = *(const short8*)&At[(wm + 16 * i + l16) * 32 + physq];
#pragma unroll
    for (int j = 0; j < 4; j++)
      bf[j] = *(const short8*)&Bt[(wn + 16 * j + l16) * 32 + physq];
#pragma unroll
    for (int i = 0; i < 4; i++)
#pragma unroll
      for (int j = 0; j < 4; j++)
        acc[i][j] = __builtin_amdgcn_mfma_f32_16x16x32_bf16(
            af[i], bf[j], acc[i][j], 0, 0, 0);
  }

#pragma unroll
  for (int i = 0; i < 4; i++) {
    int m = m0 + wm + 16 * i + quad * 4;
#pragma unroll
    for (int j = 0; j < 4; j++) {
      int n = n0 + wn + 16 * j + l16;
#pragma unroll
      for (int r = 0; r < 4; r++)
        qkv[(size_t)(m + r) * NQKV + n] = acc[i][j][r];
    }
  }
}

// ---------------------------------------------------------------------------
// Kernel 2: RoPE + qk-norm -> unit-norm bf16 q,k in MFMA-fragment layouts.
// ---------------------------------------------------------------------------
__global__ __launch_bounds__(256) void rope_norm(
    const float* __restrict__ qkv,
    ushort_t* __restrict__ qf, ushort_t* __restrict__ kf) {
  const int NQ = B_ * T_ * H_;
  int vec = blockIdx.x * 4 + (threadIdx.x >> 6);
  int d = threadIdx.x & 63;

  size_t src; int t, b, isq; ushort_t* dstbase;
  if (vec < NQ) {
    int h = vec % H_; int bt = vec / H_;
    t = bt % T_; b = bt / T_;
    src = (size_t)bt * NQKV + h * 64 + d;
    dstbase = qf + (size_t)(b * 16 + h) * 131072;
    isq = 1;
  } else {
    int vk = vec - NQ;
    int g = vk % G_; int bt = vk / G_;
    t = bt % T_; b = bt / T_;
    src = (size_t)bt * NQKV + 1024 + g * 64 + d;
    dstbase = kf + (size_t)(b * 4 + g) * 131072;
    isq = 0;
  }
  float val = qkv[src];
  int i = d & 31;
  float inv = exp2f(-(float)i * 0.4152410118074239f);  // log2(10000)/32
  float ang = (float)t * inv;
  float sn, cs;
  __sincosf(ang, &sn, &cs);
  float partner = __shfl(val, d ^ 32, 64);
  float r = (d < 32) ? (val * cs - partner * sn) : (val * cs + partner * sn);
  float ss = r * r;
#pragma unroll
  for (int off = 32; off; off >>= 1) ss += __shfl_xor(ss, off, 64);
  r *= 1.0f / (sqrtf(ss) + 1e-6f);

  int kt = t >> 6, tt = t & 63;
  int l16v = tt & 15;
  int ks = d >> 5, quad = (d >> 3) & 3, j = d & 7;
  size_t off2;
  if (isq) {
    int wavei = tt >> 4;
    off2 = ((size_t)(kt * 8 + wavei * 2 + ks) * 4 + quad) * 128 + l16v * 8 + j;
  } else {
    int nt = tt >> 4;
    off2 = ((size_t)(kt * 8 + ks * 4 + nt) * 4 + quad) * 128 + l16v * 8 + j;
  }
  dstbase[off2] = f2bf(r);
}

// ---------------------------------------------------------------------------
// Kernel 2b: V scatter + bf16 cast into PV B-fragment layout.
// ---------------------------------------------------------------------------
__global__ __launch_bounds__(256) void vscatter(
    const float* __restrict__ qkv, ushort_t* __restrict__ vf) {
  int idx = blockIdx.x * 256 + threadIdx.x;   // 2,097,152
  int dv = idx & 127;
  int t = (idx >> 7) & 2047;
  int g = (idx >> 18) & 3;
  int b = idx >> 20;
  size_t src = (size_t)(b * T_ + t) * NQKV + 1280 + g * 128 + dv;
  float v = qkv[src];
  int kt = t >> 6, ks = (t >> 5) & 1, quad = (t >> 3) & 3, j = t & 7;
  int nv = dv >> 4, l16v = dv & 15;
  size_t off = ((size_t)(kt * 16 + ks * 8 + nv) * 4 + quad) * 128 + l16v * 8 + j;
  vf[(size_t)(b * 4 + g) * 262144 + off] = f2bf(v);
}

// ---------------------------------------------------------------------------
// Kernel 3: bf16-MFMA causal flash attention, fixed-max softmax (m = gsc).
// Fully barrier-free: 128 Q rows/block, 32 rows/wave (2 row-fragments share
// each K/V fragment load -> half the L2 traffic, 52 MFMA per 24 loads).
// Per-wave causal loop bound; ones-column B-fragment built in registers.
// ---------------------------------------------------------------------------
__global__ __launch_bounds__(256, 2) void attn(
    const ushort_t* __restrict__ qf, const ushort_t* __restrict__ kf,
    const ushort_t* __restrict__ vf, const float* __restrict__ lobo,
    const float* __restrict__ qknf, float* __restrict__ y) {
  const int f = blockIdx.x;            // 512 blocks
  const int b = f >> 8;
  const int h = (f >> 4) & 15;
  const int qt = ((f & 15) + (f >> 5)) & 15;   // 128-row tile, CU-spread
  const int g = h >> 2;

  __shared__ ushort_t Ps[4 * 2176];    // per-wave 2 sets x 16 rows x 68

  const int tid = threadIdx.x;
  const int wave = tid >> 6, lane = tid & 63;
  const int quad = lane >> 4, l16 = lane & 15;
  const int R0 = qt * 128 + wave * 32;           // wave's first Q row
  ushort_t* PsW = &Ps[wave * 2176];

  // ones-column B-fragment in registers: B[k][n]=1 iff n==0
  short8 bones;
  {
    short bv = (l16 == 0) ? (short)0x3F80 : (short)0;
#pragma unroll
    for (int j = 0; j < 8; j++) bones[j] = bv;
  }

  // Q A-fragments: 4 consecutive 512-elem blocks starting at
  // ((b,h) base) + (qt32*8 + (wave&1)*4)*512,  qt32 = R0/64.
  const int qt32 = R0 >> 6;
  const ushort_t* qb = qf + (size_t)(b * 16 + h) * 131072 +
                       ((size_t)(qt32 * 8 + (wave & 1) * 4)) * 512 + lane * 8;
  short8 aq[4];
#pragma unroll
  for (int j = 0; j < 4; j++) aq[j] = *(const short8*)&qb[j * 512];

  f32x4 oA[9], oB[9];
#pragma unroll
  for (int nv = 0; nv < 9; nv++) {
    oA[nv] = (f32x4){0.f, 0.f, 0.f, 0.f};
    oB[nv] = (f32x4){0.f, 0.f, 0.f, 0.f};
  }

  const float gsc = qknf[0];
  const float sinkp = __expf(lobo[h] - gsc);

  const ushort_t* kt0 = kf + (size_t)(b * 4 + g) * 131072 + lane * 8;
  const ushort_t* vt0 = vf + (size_t)(b * 4 + g) * 262144 + lane * 8;
  const int ktmax = (R0 + 31) >> 6;

  for (int kt = 0; kt <= ktmax; kt++) {
    const ushort_t* kg = kt0 + (size_t)kt * 4096;
    const ushort_t* vg = vt0 + (size_t)kt * 8192;
    short8 kfr[8];
#pragma unroll
    for (int u = 0; u < 8; u++) kfr[u] = *(const short8*)&kg[u * 512];
    short8 vfr[16];
#pragma unroll
    for (int u = 0; u < 16; u++) vfr[u] = *(const short8*)&vg[u * 512];

    f32x4 sA[4], sB[4];
#pragma unroll
    for (int nt = 0; nt < 4; nt++) {
      sA[nt] = (f32x4){0.f, 0.f, 0.f, 0.f};
      sB[nt] = (f32x4){0.f, 0.f, 0.f, 0.f};
    }
#pragma unroll
    for (int nt = 0; nt < 4; nt++) {
      sA[nt] = __builtin_amdgcn_mfma_f32_16x16x32_bf16(aq[0], kfr[nt], sA[nt], 0, 0, 0);
      sB[nt] = __builtin_amdgcn_mfma_f32_16x16x32_bf16(aq[2], kfr[nt], sB[nt], 0, 0, 0);
    }
#pragma unroll
    for (int nt = 0; nt < 4; nt++) {
      sA[nt] = __builtin_amdgcn_mfma_f32_16x16x32_bf16(aq[1], kfr[4 + nt], sA[nt], 0, 0, 0);
      sB[nt] = __builtin_amdgcn_mfma_f32_16x16x32_bf16(aq[3], kfr[4 + nt], sB[nt], 0, 0, 0);
    }

    // fixed-max softmax p = exp(gsc*(s-1)), causal predicate key<=row
    const int keyb = kt * 64 + l16;
#pragma unroll
    for (int nt = 0; nt < 4; nt++) {
      int key = keyb + nt * 16;
#pragma unroll
      for (int r = 0; r < 4; r++) {
        int rowA = R0 + quad * 4 + r;
        float pA = (key <= rowA) ? __expf((sA[nt][r] - 1.0f) * gsc) : 0.f;
        float pB = (key <= rowA + 16) ? __expf((sB[nt][r] - 1.0f) * gsc) : 0.f;
        PsW[(quad * 4 + r) * 68 + nt * 16 + l16] = f2bf(pA);
        PsW[1088 + (quad * 4 + r) * 68 + nt * 16 + l16] = f2bf(pB);
      }
    }

    short8 apA0 = *(const short8*)&PsW[l16 * 68 + quad * 8];
    short8 apA1 = *(const short8*)&PsW[l16 * 68 + 32 + quad * 8];
    short8 apB0 = *(const short8*)&PsW[1088 + l16 * 68 + quad * 8];
    short8 apB1 = *(const short8*)&PsW[1088 + l16 * 68 + 32 + quad * 8];

#pragma unroll
    for (int nv = 0; nv < 8; nv++) {
      oA[nv] = __builtin_amdgcn_mfma_f32_16x16x32_bf16(apA0, vfr[nv], oA[nv], 0, 0, 0);
      oB[nv] = __builtin_amdgcn_mfma_f32_16x16x32_bf16(apB0, vfr[nv], oB[nv], 0, 0, 0);
    }
    oA[8] = __builtin_amdgcn_mfma_f32_16x16x32_bf16(apA0, bones, oA[8], 0, 0, 0);
    oA[8] = __builtin_amdgcn_mfma_f32_16x16x32_bf16(apA1, bones, oA[8], 0, 0, 0);
    oB[8] = __builtin_amdgcn_mfma_f32_16x16x32_bf16(apB0, bones, oB[8], 0, 0, 0);
    oB[8] = __builtin_amdgcn_mfma_f32_16x16x32_bf16(apB1, bones, oB[8], 0, 0, 0);
#pragma unroll
    for (int nv = 0; nv < 8; nv++) {
      oA[nv] = __builtin_amdgcn_mfma_f32_16x16x32_bf16(apA1, vfr[8 + nv], oA[nv], 0, 0, 0);
      oB[nv] = __builtin_amdgcn_mfma_f32_16x16x32_bf16(apB1, vfr[8 + nv], oB[nv], 0, 0, 0);
    }
  }

  // epilogue: l = sink + mfma row-sum (col 0 of o[8]); normalize; head-sum
#pragma unroll
  for (int r = 0; r < 4; r++) {
    float lmA = __shfl(oA[8][r], lane & 48, 64);
    float lmB = __shfl(oB[8][r], lane & 48, 64);
    float invlA = 1.0f / (lmA + sinkp);
    float invlB = 1.0f / (lmB + sinkp);
    size_t rowA = (size_t)b * T_ + R0 + quad * 4 + r;
#pragma unroll
    for (int nv = 0; nv < 8; nv++) {
      atomicAdd(&y[rowA * 128 + nv * 16 + l16], oA[nv][r] * invlA);
      atomicAdd(&y[(rowA + 16) * 128 + nv * 16 + l16], oB[nv][r] * invlB);
    }
  }
}

// ---------------------------------------------------------------------------
// Kernel 4: out = y[4096][128] @ Wproj[128][1024] via bf16 MFMA.
// ---------------------------------------------------------------------------
__global__ __launch_bounds__(256) void out_proj(
    const float* __restrict__ y, const ushort_t* __restrict__ wpf,
    float* __restrict__ out) {
  __shared__ ushort_t yl[128 * 136];
  const int tid = threadIdx.x;
  const int wave = tid >> 6, lane = tid & 63;
  const int quad = lane >> 4, l16 = lane & 15;
  const int n0 = blockIdx.x * 128, m0 = blockIdx.y * 128;
  const int wm = (wave & 1) * 64, wn = (wave >> 1) * 64;

#pragma unroll
  for (int it = 0; it < 8; it++) {
    int p = it * 256 + tid;
    int row = p >> 4, c8 = p & 15;
    const float* src = &y[(size_t)(m0 + row) * 128 + c8 * 8];
    float4 v0 = *(const float4*)&src[0];
    float4 v1 = *(const float4*)&src[4];
    float fv[8] = {v0.x, v0.y, v0.z, v0.w, v1.x, v1.y, v1.z, v1.w};
    short8 hv;
#pragma unroll
    for (int c = 0; c < 8; c++) hv[c] = (short)f2bf(fv[c]);
    *(short8*)&yl[row * 136 + c8 * 8] = hv;
  }
  __syncthreads();

  f32x4 acc[4][4];
#pragma unroll
  for (int i = 0; i < 4; i++)
#pragma unroll
    for (int j = 0; j < 4; j++) acc[i][j] = (f32x4){0.f, 0.f, 0.f, 0.f};

#pragma unroll
  for (int ks = 0; ks < 4; ks++) {
    short8 af[4], bfr[4];
#pragma unroll
    for (int i = 0; i < 4; i++)
      af[i] = *(const short8*)&yl[(wm + 16 * i + l16) * 136 + (ks * 4 + quad) * 8];
    const ushort_t* wb = wpf + (((size_t)(n0 >> 7) * 4 + ks) * 8) * 512;
#pragma unroll
    for (int j = 0; j < 4; j++)
      bfr[j] = *(const short8*)&wb[((size_t)((wn >> 4) + j)) * 512 + lane * 8];
#pragma unroll
    for (int i = 0; i < 4; i++)
#pragma unroll
      for (int j = 0; j < 4; j++)
        acc[i][j] = __builtin_amdgcn_mfma_f32_16x16x32_bf16(
            af[i], bfr[j], acc[i][j], 0, 0, 0);
  }

#pragma unroll
  for (int i = 0; i < 4; i++) {
    int m = m0 + wm + 16 * i + quad * 4;
#pragma unroll
    for (int j = 0; j < 4; j++) {
      int n = n0 + wn + 16 * j + l16;
#pragma unroll
      for (int r = 0; r < 4; r++)
        out[(size_t)(m + r) * 1024 + n] = acc[i][j][r];
    }
  }
}

// ---------------------------------------------------------------------------
extern "C" void kernel_launch(void* const* d_in, const int* in_sizes, int n_in,
                              void* d_out, int out_size, void* d_ws, size_t ws_size,
                              hipStream_t stream) {
  const float* x     = (const float*)d_in[0];
  const float* Wq    = (const float*)d_in[2];
  const float* Wk    = (const float*)d_in[3];
  const float* Wv    = (const float*)d_in[4];
  const float* Wproj = (const float*)d_in[5];
  const float* lobo  = (const float*)d_in[6];
  const float* qknf  = (const float*)d_in[7];
  float* out = (float*)d_out;

  // ws: [qkv f32 29.4MB | xb 16.8MB | wt 7.3MB | wpf 0.25MB]; qf/kf/vf/y alias xb.
  float* qkv = (float*)d_ws;                                    // 7,340,032 f32
  ushort_t* xb = (ushort_t*)(qkv + (size_t)B_ * T_ * NQKV);     // 8,388,608 bf16
  ushort_t* wt = xb + (size_t)B_ * T_ * KS2;                    // 3,670,016 bf16
  ushort_t* wpf = wt + (size_t)NQKV * KS2;                      //   131,072 bf16
  ushort_t* qf = xb;                                            // 4,194,304 bf16
  ushort_t* kf = qf + (size_t)B_ * H_ * T_ * 64;                // 1,048,576 bf16
  ushort_t* vf = kf + (size_t)B_ * G_ * T_ * 64;                // 2,097,152 bf16
  float* y = (float*)(vf + (size_t)B_ * G_ * T_ * 128);         //   524,288 f32

  cast_x<<<(B_ * T_ * 128) / 256, 256, 0, stream>>>(x, xb);
  dim3 gw(NQKV / 64, C_ / 64);
  cast_w<<<gw, 256, 0, stream>>>(Wq, Wk, Wv, wt);
  cast_wp<<<64, 256, 0, stream>>>(Wproj, wpf);

  dim3 gg(NQKV / 128, (B_ * T_) / 128);
  gemm_qkv_mfma<<<gg, 256, 0, stream>>>(xb, wt, qkv);

  int nvec = B_ * T_ * H_ + B_ * T_ * G_;   // 81920
  rope_norm<<<nvec / 4, 256, 0, stream>>>(qkv, qf, kf);

  vscatter<<<(B_ * G_ * T_ * DV_) / 256, 256, 0, stream>>>(qkv, vf);

  (void)hipMemsetAsync(y, 0, (size_t)B_ * T_ * 128 * sizeof(float), stream);

  attn<<<B_ * H_ * (T_ / 128), 256, 0, stream>>>(qf, kf, vf, lobo, qknf, y);

  dim3 go(8, 32);
  out_proj<<<go, 256, 0, stream>>>(y, wpf, out);
}

// Round 10
// 258.095 us; speedup vs baseline: 1.1218x; 1.0835x over previous
//
#include <hip/hip_runtime.h>
#include <hip/hip_bf16.h>
#include <math.h>

#define B_ 2
#define T_ 2048
#define C_ 1024
#define H_ 16
#define G_ 4
#define DQK_ 64
#define DV_ 128
#define NQKV 1792   // H*DQK + G*DQK + G*DV
#define KS2 2048    // compact split storage: [hi | lo]
// Variable-K split GEMM: Q/K columns (n<1280) use 64 tiles
// (hi·hi 0..31, lo·hi 32..63); V columns (n>=1280) use 32 (hi·hi only —
// V is rounded to bf16 downstream so the corrections are noise).
// ca = kt*32 (hi then lo contiguous in xb); cb = (kt<32?kt:kt-32)*32.
// Operand rows chunk-XOR-swizzled: chunk c of row r at phys chunk c^((r>>1)&3).

typedef __attribute__((ext_vector_type(8))) short short8;
typedef __attribute__((ext_vector_type(4))) float f32x4;
typedef unsigned short ushort_t;

__device__ inline ushort_t f2bf(float f) {
  union { float f; unsigned int u; } v; v.f = f;
  unsigned int r = (v.u + 0x7FFFu + ((v.u >> 16) & 1u)) >> 16;  // RNE
  return (ushort_t)r;
}
__device__ inline float bf2f(ushort_t h) {
  union { unsigned int u; float f; } v; v.u = ((unsigned int)h) << 16;
  return v.f;
}

#define GLD_LDS16(g, l)                                              \
  __builtin_amdgcn_global_load_lds(                                  \
      (const __attribute__((address_space(1))) void*)(g),            \
      (__attribute__((address_space(3))) void*)(l), 16, 0, 0)

// ---------------------------------------------------------------------------
// Kernel 0a: split-cast x -> xb[4096][2048] bf16 = [x_hi | x_lo], swizzled.
// ---------------------------------------------------------------------------
__global__ __launch_bounds__(256) void cast_x(
    const float* __restrict__ x, ushort_t* __restrict__ xb) {
  int idx = blockIdx.x * 256 + threadIdx.x;   // 524288
  int m = idx >> 7;
  int c8 = idx & 127;
  const float* src = &x[(size_t)m * 1024 + c8 * 8];
  float4 v0 = *(const float4*)&src[0];
  float4 v1 = *(const float4*)&src[4];
  float f[8] = {v0.x, v0.y, v0.z, v0.w, v1.x, v1.y, v1.z, v1.w};
  short8 hv, lv;
#pragma unroll
  for (int c = 0; c < 8; c++) {
    ushort_t h = f2bf(f[c]);
    hv[c] = (short)h;
    lv[c] = (short)f2bf(f[c] - bf2f(h));
  }
  int key = (m >> 1) & 3;
  int phys = (c8 & ~3) * 8 + ((c8 & 3) ^ key) * 8;
  ushort_t* row = xb + (size_t)m * KS2;
  *(short8*)&row[phys] = hv;
  *(short8*)&row[1024 + phys] = lv;
}

// ---------------------------------------------------------------------------
// Kernel 0b: transpose+cast W -> wt[1792][2048] bf16 (hi half only), swizzled.
// ---------------------------------------------------------------------------
__global__ __launch_bounds__(256) void cast_w(
    const float* __restrict__ Wq, const float* __restrict__ Wk,
    const float* __restrict__ Wv, ushort_t* __restrict__ wt) {
  __shared__ float tile[64][65];
  const int n0 = blockIdx.x * 64;
  const int k0 = blockIdx.y * 64;
  const int tid = threadIdx.x;

  const float* Wp; int ldw, noff;
  if (n0 < 1024)      { Wp = Wq; ldw = 1024; noff = n0; }
  else if (n0 < 1280) { Wp = Wk; ldw = 256;  noff = n0 - 1024; }
  else                { Wp = Wv; ldw = 512;  noff = n0 - 1280; }

#pragma unroll
  for (int it = 0; it < 4; it++) {
    int fi = it * 256 + tid;
    int kk = fi >> 4;
    int nc = (fi & 15) * 4;
    float4 v = *(const float4*)&Wp[(size_t)(k0 + kk) * ldw + noff + nc];
    tile[nc + 0][kk] = v.x; tile[nc + 1][kk] = v.y;
    tile[nc + 2][kk] = v.z; tile[nc + 3][kk] = v.w;
  }
  __syncthreads();
  int nn = tid >> 2, seg = tid & 3;
  int n = n0 + nn;
  int key = (n >> 1) & 3;
  ushort_t* row = wt + (size_t)n * KS2;
#pragma unroll
  for (int j = 0; j < 2; j++) {
    short8 hv;
#pragma unroll
    for (int u = 0; u < 8; u++)
      hv[u] = (short)f2bf(tile[nn][seg * 16 + j * 8 + u]);
    int c8 = (k0 >> 3) + seg * 2 + j;
    int phys = (c8 & ~3) * 8 + ((c8 & 3) ^ key) * 8;
    *(short8*)&row[phys] = hv;
  }
}

// ---------------------------------------------------------------------------
// Kernel 0c: cast Wproj[128][1024] -> bf16 B-fragment order.
// ---------------------------------------------------------------------------
__global__ __launch_bounds__(256) void cast_wp(
    const float* __restrict__ Wp, ushort_t* __restrict__ wpf) {
  int idx = blockIdx.x * 256 + threadIdx.x;   // 16384
  int n = idx & 1023;
  int kc = idx >> 10;                          // 0..15 (chunk of 8 k's)
  short8 v;
#pragma unroll
  for (int j = 0; j < 8; j++)
    v[j] = (short)f2bf(Wp[(size_t)(kc * 8 + j) * 1024 + n]);
  size_t off = (((size_t)(n >> 7) * 4 + (kc >> 2)) * 8 + ((n >> 4) & 7)) * 512 +
               ((kc & 3) * 16 + (n & 15)) * 8;
  *(short8*)&wpf[off] = v;
}

// ---------------------------------------------------------------------------
// Kernel 1: bf16-MFMA QKV GEMM.  2-barrier single-buffer K-loop +
// conflict-free swizzled LDS; variable K per column group (64 QK / 32 V).
// ---------------------------------------------------------------------------
__global__ __launch_bounds__(256) void gemm_qkv_mfma(
    const ushort_t* __restrict__ xb, const ushort_t* __restrict__ wt,
    float* __restrict__ qkv) {
  __shared__ ushort_t At[128 * 32];
  __shared__ ushort_t Bt[128 * 32];
  const int tid = threadIdx.x;
  const int wave = tid >> 6, lane = tid & 63;
  const int quad = lane >> 4, l16 = lane & 15;
  const int m0 = blockIdx.y * 128, n0 = blockIdx.x * 128;
  const int wm = (wave & 1) * 64, wn = (wave >> 1) * 64;
  const int physq = (quad ^ ((l16 >> 1) & 3)) * 8;   // de-swizzle read column
  const int ntiles = (n0 >= 1280) ? 32 : 64;

  f32x4 acc[4][4];
#pragma unroll
  for (int i = 0; i < 4; i++)
#pragma unroll
    for (int j = 0; j < 4; j++) acc[i][j] = (f32x4){0.f, 0.f, 0.f, 0.f};

  const int rA = wave * 32 + (lane >> 2);
  const int cA = (lane & 3) * 8;
  const ushort_t* gA = xb + (size_t)(m0 + rA) * KS2 + cA;
  const ushort_t* gB = wt + (size_t)(n0 + rA) * KS2 + cA;
  ushort_t* lA0 = At + (size_t)(wave * 32) * 32;
  ushort_t* lA1 = At + (size_t)(wave * 32 + 16) * 32;
  ushort_t* lB0 = Bt + (size_t)(wave * 32) * 32;
  ushort_t* lB1 = Bt + (size_t)(wave * 32 + 16) * 32;

  for (int kt = 0; kt < ntiles; kt++) {
    const int ca = kt * 32;
    const int cb = (kt < 32 ? kt : kt - 32) * 32;
    __syncthreads();
    GLD_LDS16(gA + ca, lA0);
    GLD_LDS16(gA + ca + 16 * KS2, lA1);
    GLD_LDS16(gB + cb, lB0);
    GLD_LDS16(gB + cb + 16 * KS2, lB1);
    __syncthreads();

    short8 af[4], bf[4];
#pragma unroll
    for (int i = 0; i < 4; i++)
      af[i] = *(const short8*)&At[(wm + 16 * i + l16) * 32 + physq];
#pragma unroll
    for (int j = 0; j < 4; j++)
      bf[j] = *(const short8*)&Bt[(wn + 16 * j + l16) * 32 + physq];
#pragma unroll
    for (int i = 0; i < 4; i++)
#pragma unroll
      for (int j = 0; j < 4; j++)
        acc[i][j] = __builtin_amdgcn_mfma_f32_16x16x32_bf16(
            af[i], bf[j], acc[i][j], 0, 0, 0);
  }

#pragma unroll
  for (int i = 0; i < 4; i++) {
    int m = m0 + wm + 16 * i + quad * 4;
#pragma unroll
    for (int j = 0; j < 4; j++) {
      int n = n0 + wn + 16 * j + l16;
#pragma unroll
      for (int r = 0; r < 4; r++)
        qkv[(size_t)(m + r) * NQKV + n] = acc[i][j][r];
    }
  }
}

// ---------------------------------------------------------------------------
// Kernel 2: RoPE + qk-norm -> unit-norm bf16 q,k in MFMA-fragment layouts.
// ---------------------------------------------------------------------------
__global__ __launch_bounds__(256) void rope_norm(
    const float* __restrict__ qkv,
    ushort_t* __restrict__ qf, ushort_t* __restrict__ kf) {
  const int NQ = B_ * T_ * H_;
  int vec = blockIdx.x * 4 + (threadIdx.x >> 6);
  int d = threadIdx.x & 63;

  size_t src; int t, b, isq; ushort_t* dstbase;
  if (vec < NQ) {
    int h = vec % H_; int bt = vec / H_;
    t = bt % T_; b = bt / T_;
    src = (size_t)bt * NQKV + h * 64 + d;
    dstbase = qf + (size_t)(b * 16 + h) * 131072;
    isq = 1;
  } else {
    int vk = vec - NQ;
    int g = vk % G_; int bt = vk / G_;
    t = bt % T_; b = bt / T_;
    src = (size_t)bt * NQKV + 1024 + g * 64 + d;
    dstbase = kf + (size_t)(b * 4 + g) * 131072;
    isq = 0;
  }
  float val = qkv[src];
  int i = d & 31;
  float inv = exp2f(-(float)i * 0.4152410118074239f);  // log2(10000)/32
  float ang = (float)t * inv;
  float sn, cs;
  __sincosf(ang, &sn, &cs);
  float partner = __shfl(val, d ^ 32, 64);
  float r = (d < 32) ? (val * cs - partner * sn) : (val * cs + partner * sn);
  float ss = r * r;
#pragma unroll
  for (int off = 32; off; off >>= 1) ss += __shfl_xor(ss, off, 64);
  r *= 1.0f / (sqrtf(ss) + 1e-6f);

  int kt = t >> 6, tt = t & 63;
  int l16v = tt & 15;
  int ks = d >> 5, quad = (d >> 3) & 3, j = d & 7;
  size_t off2;
  if (isq) {
    int wavei = tt >> 4;
    off2 = ((size_t)(kt * 8 + wavei * 2 + ks) * 4 + quad) * 128 + l16v * 8 + j;
  } else {
    int nt = tt >> 4;
    off2 = ((size_t)(kt * 8 + ks * 4 + nt) * 4 + quad) * 128 + l16v * 8 + j;
  }
  dstbase[off2] = f2bf(r);
}

// ---------------------------------------------------------------------------
// Kernel 2b: V scatter + bf16 cast into PV B-fragment layout.
// ---------------------------------------------------------------------------
__global__ __launch_bounds__(256) void vscatter(
    const float* __restrict__ qkv, ushort_t* __restrict__ vf) {
  int idx = blockIdx.x * 256 + threadIdx.x;   // 2,097,152
  int dv = idx & 127;
  int t = (idx >> 7) & 2047;
  int g = (idx >> 18) & 3;
  int b = idx >> 20;
  size_t src = (size_t)(b * T_ + t) * NQKV + 1280 + g * 128 + dv;
  float v = qkv[src];
  int kt = t >> 6, ks = (t >> 5) & 1, quad = (t >> 3) & 3, j = t & 7;
  int nv = dv >> 4, l16v = dv & 15;
  size_t off = ((size_t)(kt * 16 + ks * 8 + nv) * 4 + quad) * 128 + l16v * 8 + j;
  vf[(size_t)(b * 4 + g) * 262144 + off] = f2bf(v);
}

// ---------------------------------------------------------------------------
// Kernel 3: bf16-MFMA causal flash attention, fixed-max softmax (m = gsc).
// Fully barrier-free: 128 Q rows/block, 32 rows/wave; ones-column in regs.
// ---------------------------------------------------------------------------
__global__ __launch_bounds__(256, 2) void attn(
    const ushort_t* __restrict__ qf, const ushort_t* __restrict__ kf,
    const ushort_t* __restrict__ vf, const float* __restrict__ lobo,
    const float* __restrict__ qknf, float* __restrict__ y) {
  const int f = blockIdx.x;            // 512 blocks
  const int b = f >> 8;
  const int h = (f >> 4) & 15;
  const int qt = ((f & 15) + (f >> 5)) & 15;   // 128-row tile, CU-spread
  const int g = h >> 2;

  __shared__ ushort_t Ps[4 * 2176];    // per-wave 2 sets x 16 rows x 68

  const int tid = threadIdx.x;
  const int wave = tid >> 6, lane = tid & 63;
  const int quad = lane >> 4, l16 = lane & 15;
  const int R0 = qt * 128 + wave * 32;           // wave's first Q row
  ushort_t* PsW = &Ps[wave * 2176];

  short8 bones;
  {
    short bv = (l16 == 0) ? (short)0x3F80 : (short)0;
#pragma unroll
    for (int j = 0; j < 8; j++) bones[j] = bv;
  }

  const int qt32 = R0 >> 6;
  const ushort_t* qb = qf + (size_t)(b * 16 + h) * 131072 +
                       ((size_t)(qt32 * 8 + (wave & 1) * 4)) * 512 + lane * 8;
  short8 aq[4];
#pragma unroll
  for (int j = 0; j < 4; j++) aq[j] = *(const short8*)&qb[j * 512];

  f32x4 oA[9], oB[9];
#pragma unroll
  for (int nv = 0; nv < 9; nv++) {
    oA[nv] = (f32x4){0.f, 0.f, 0.f, 0.f};
    oB[nv] = (f32x4){0.f, 0.f, 0.f, 0.f};
  }

  const float gsc = qknf[0];
  const float sinkp = __expf(lobo[h] - gsc);

  const ushort_t* kt0 = kf + (size_t)(b * 4 + g) * 131072 + lane * 8;
  const ushort_t* vt0 = vf + (size_t)(b * 4 + g) * 262144 + lane * 8;
  const int ktmax = (R0 + 31) >> 6;

  for (int kt = 0; kt <= ktmax; kt++) {
    const ushort_t* kg = kt0 + (size_t)kt * 4096;
    const ushort_t* vg = vt0 + (size_t)kt * 8192;
    short8 kfr[8];
#pragma unroll
    for (int u = 0; u < 8; u++) kfr[u] = *(const short8*)&kg[u * 512];
    short8 vfr[16];
#pragma unroll
    for (int u = 0; u < 16; u++) vfr[u] = *(const short8*)&vg[u * 512];

    f32x4 sA[4], sB[4];
#pragma unroll
    for (int nt = 0; nt < 4; nt++) {
      sA[nt] = (f32x4){0.f, 0.f, 0.f, 0.f};
      sB[nt] = (f32x4){0.f, 0.f, 0.f, 0.f};
    }
#pragma unroll
    for (int nt = 0; nt < 4; nt++) {
      sA[nt] = __builtin_amdgcn_mfma_f32_16x16x32_bf16(aq[0], kfr[nt], sA[nt], 0, 0, 0);
      sB[nt] = __builtin_amdgcn_mfma_f32_16x16x32_bf16(aq[2], kfr[nt], sB[nt], 0, 0, 0);
    }
#pragma unroll
    for (int nt = 0; nt < 4; nt++) {
      sA[nt] = __builtin_amdgcn_mfma_f32_16x16x32_bf16(aq[1], kfr[4 + nt], sA[nt], 0, 0, 0);
      sB[nt] = __builtin_amdgcn_mfma_f32_16x16x32_bf16(aq[3], kfr[4 + nt], sB[nt], 0, 0, 0);
    }

    const int keyb = kt * 64 + l16;
#pragma unroll
    for (int nt = 0; nt < 4; nt++) {
      int key = keyb + nt * 16;
#pragma unroll
      for (int r = 0; r < 4; r++) {
        int rowA = R0 + quad * 4 + r;
        float pA = (key <= rowA) ? __expf((sA[nt][r] - 1.0f) * gsc) : 0.f;
        float pB = (key <= rowA + 16) ? __expf((sB[nt][r] - 1.0f) * gsc) : 0.f;
        PsW[(quad * 4 + r) * 68 + nt * 16 + l16] = f2bf(pA);
        PsW[1088 + (quad * 4 + r) * 68 + nt * 16 + l16] = f2bf(pB);
      }
    }

    short8 apA0 = *(const short8*)&PsW[l16 * 68 + quad * 8];
    short8 apA1 = *(const short8*)&PsW[l16 * 68 + 32 + quad * 8];
    short8 apB0 = *(const short8*)&PsW[1088 + l16 * 68 + quad * 8];
    short8 apB1 = *(const short8*)&PsW[1088 + l16 * 68 + 32 + quad * 8];

#pragma unroll
    for (int nv = 0; nv < 8; nv++) {
      oA[nv] = __builtin_amdgcn_mfma_f32_16x16x32_bf16(apA0, vfr[nv], oA[nv], 0, 0, 0);
      oB[nv] = __builtin_amdgcn_mfma_f32_16x16x32_bf16(apB0, vfr[nv], oB[nv], 0, 0, 0);
    }
    oA[8] = __builtin_amdgcn_mfma_f32_16x16x32_bf16(apA0, bones, oA[8], 0, 0, 0);
    oA[8] = __builtin_amdgcn_mfma_f32_16x16x32_bf16(apA1, bones, oA[8], 0, 0, 0);
    oB[8] = __builtin_amdgcn_mfma_f32_16x16x32_bf16(apB0, bones, oB[8], 0, 0, 0);
    oB[8] = __builtin_amdgcn_mfma_f32_16x16x32_bf16(apB1, bones, oB[8], 0, 0, 0);
#pragma unroll
    for (int nv = 0; nv < 8; nv++) {
      oA[nv] = __builtin_amdgcn_mfma_f32_16x16x32_bf16(apA1, vfr[8 + nv], oA[nv], 0, 0, 0);
      oB[nv] = __builtin_amdgcn_mfma_f32_16x16x32_bf16(apB1, vfr[8 + nv], oB[nv], 0, 0, 0);
    }
  }

#pragma unroll
  for (int r = 0; r < 4; r++) {
    float lmA = __shfl(oA[8][r], lane & 48, 64);
    float lmB = __shfl(oB[8][r], lane & 48, 64);
    float invlA = 1.0f / (lmA + sinkp);
    float invlB = 1.0f / (lmB + sinkp);
    size_t rowA = (size_t)b * T_ + R0 + quad * 4 + r;
#pragma unroll
    for (int nv = 0; nv < 8; nv++) {
      atomicAdd(&y[rowA * 128 + nv * 16 + l16], oA[nv][r] * invlA);
      atomicAdd(&y[(rowA + 16) * 128 + nv * 16 + l16], oB[nv][r] * invlB);
    }
  }
}

// ---------------------------------------------------------------------------
// Kernel 4: out = y[4096][128] @ Wproj[128][1024] via bf16 MFMA.
// ---------------------------------------------------------------------------
__global__ __launch_bounds__(256) void out_proj(
    const float* __restrict__ y, const ushort_t* __restrict__ wpf,
    float* __restrict__ out) {
  __shared__ ushort_t yl[128 * 136];
  const int tid = threadIdx.x;
  const int wave = tid >> 6, lane = tid & 63;
  const int quad = lane >> 4, l16 = lane & 15;
  const int n0 = blockIdx.x * 128, m0 = blockIdx.y * 128;
  const int wm = (wave & 1) * 64, wn = (wave >> 1) * 64;

#pragma unroll
  for (int it = 0; it < 8; it++) {
    int p = it * 256 + tid;
    int row = p >> 4, c8 = p & 15;
    const float* src = &y[(size_t)(m0 + row) * 128 + c8 * 8];
    float4 v0 = *(const float4*)&src[0];
    float4 v1 = *(const float4*)&src[4];
    float fv[8] = {v0.x, v0.y, v0.z, v0.w, v1.x, v1.y, v1.z, v1.w};
    short8 hv;
#pragma unroll
    for (int c = 0; c < 8; c++) hv[c] = (short)f2bf(fv[c]);
    *(short8*)&yl[row * 136 + c8 * 8] = hv;
  }
  __syncthreads();

  f32x4 acc[4][4];
#pragma unroll
  for (int i = 0; i < 4; i++)
#pragma unroll
    for (int j = 0; j < 4; j++) acc[i][j] = (f32x4){0.f, 0.f, 0.f, 0.f};

#pragma unroll
  for (int ks = 0; ks < 4; ks++) {
    short8 af[4], bfr[4];
#pragma unroll
    for (int i = 0; i < 4; i++)
      af[i] = *(const short8*)&yl[(wm + 16 * i + l16) * 136 + (ks * 4 + quad) * 8];
    const ushort_t* wb = wpf + (((size_t)(n0 >> 7) * 4 + ks) * 8) * 512;
#pragma unroll
    for (int j = 0; j < 4; j++)
      bfr[j] = *(const short8*)&wb[((size_t)((wn >> 4) + j)) * 512 + lane * 8];
#pragma unroll
    for (int i = 0; i < 4; i++)
#pragma unroll
      for (int j = 0; j < 4; j++)
        acc[i][j] = __builtin_amdgcn_mfma_f32_16x16x32_bf16(
            af[i], bfr[j], acc[i][j], 0, 0, 0);
  }

#pragma unroll
  for (int i = 0; i < 4; i++) {
    int m = m0 + wm + 16 * i + quad * 4;
#pragma unroll
    for (int j = 0; j < 4; j++) {
      int n = n0 + wn + 16 * j + l16;
#pragma unroll
      for (int r = 0; r < 4; r++)
        out[(size_t)(m + r) * 1024 + n] = acc[i][j][r];
    }
  }
}

// ---------------------------------------------------------------------------
extern "C" void kernel_launch(void* const* d_in, const int* in_sizes, int n_in,
                              void* d_out, int out_size, void* d_ws, size_t ws_size,
                              hipStream_t stream) {
  const float* x     = (const float*)d_in[0];
  const float* Wq    = (const float*)d_in[2];
  const float* Wk    = (const float*)d_in[3];
  const float* Wv    = (const float*)d_in[4];
  const float* Wproj = (const float*)d_in[5];
  const float* lobo  = (const float*)d_in[6];
  const float* qknf  = (const float*)d_in[7];
  float* out = (float*)d_out;

  // ws: [qkv f32 29.4MB | xb 16.8MB | wt 7.3MB | wpf 0.25MB]; qf/kf/vf/y alias xb.
  float* qkv = (float*)d_ws;                                    // 7,340,032 f32
  ushort_t* xb = (ushort_t*)(qkv + (size_t)B_ * T_ * NQKV);     // 8,388,608 bf16
  ushort_t* wt = xb + (size_t)B_ * T_ * KS2;                    // 3,670,016 bf16
  ushort_t* wpf = wt + (size_t)NQKV * KS2;                      //   131,072 bf16
  ushort_t* qf = xb;                                            // 4,194,304 bf16
  ushort_t* kf = qf + (size_t)B_ * H_ * T_ * 64;                // 1,048,576 bf16
  ushort_t* vf = kf + (size_t)B_ * G_ * T_ * 64;                // 2,097,152 bf16
  float* y = (float*)(vf + (size_t)B_ * G_ * T_ * 128);         //   524,288 f32

  cast_x<<<(B_ * T_ * 128) / 256, 256, 0, stream>>>(x, xb);
  dim3 gw(NQKV / 64, C_ / 64);
  cast_w<<<gw, 256, 0, stream>>>(Wq, Wk, Wv, wt);
  cast_wp<<<64, 256, 0, stream>>>(Wproj, wpf);

  dim3 gg(NQKV / 128, (B_ * T_) / 128);
  gemm_qkv_mfma<<<gg, 256, 0, stream>>>(xb, wt, qkv);

  int nvec = B_ * T_ * H_ + B_ * T_ * G_;   // 81920
  rope_norm<<<nvec / 4, 256, 0, stream>>>(qkv, qf, kf);

  vscatter<<<(B_ * G_ * T_ * DV_) / 256, 256, 0, stream>>>(qkv, vf);

  (void)hipMemsetAsync(y, 0, (size_t)B_ * T_ * 128 * sizeof(float), stream);

  attn<<<B_ * H_ * (T_ / 128), 256, 0, stream>>>(qf, kf, vf, lobo, qknf, y);

  dim3 go(8, 32);
  out_proj<<<go, 256, 0, stream>>>(y, wpf, out);
}

// Round 11
// 251.212 us; speedup vs baseline: 1.1526x; 1.0274x over previous
//
#include <hip/hip_runtime.h>
#include <hip/hip_bf16.h>
#include <math.h>

#define B_ 2
#define T_ 2048
#define C_ 1024
#define H_ 16
#define G_ 4
#define DQK_ 64
#define DV_ 128
#define NQKV 1792   // H*DQK + G*DQK + G*DV
#define KS2 2048    // compact split storage: [hi | lo]
// Variable-K split GEMM: Q/K columns (n<1280) use 64 tiles
// (hi·hi 0..31, lo·hi 32..63); V columns (n>=1280) use 32 (hi·hi only).
// Operand rows chunk-XOR-swizzled: chunk c of row r at phys chunk c^((r>>1)&3).

typedef __attribute__((ext_vector_type(8))) short short8;
typedef __attribute__((ext_vector_type(4))) float f32x4;
typedef unsigned short ushort_t;

__device__ inline ushort_t f2bf(float f) {
  union { float f; unsigned int u; } v; v.f = f;
  unsigned int r = (v.u + 0x7FFFu + ((v.u >> 16) & 1u)) >> 16;  // RNE
  return (ushort_t)r;
}
__device__ inline float bf2f(ushort_t h) {
  union { unsigned int u; float f; } v; v.u = ((unsigned int)h) << 16;
  return v.f;
}

#define GLD_LDS16(g, l)                                              \
  __builtin_amdgcn_global_load_lds(                                  \
      (const __attribute__((address_space(1))) void*)(g),            \
      (__attribute__((address_space(3))) void*)(l), 16, 0, 0)

// ---------------------------------------------------------------------------
// Kernel 0a: split-cast x -> xb[4096][2048] bf16 = [x_hi | x_lo], swizzled.
// ---------------------------------------------------------------------------
__global__ __launch_bounds__(256) void cast_x(
    const float* __restrict__ x, ushort_t* __restrict__ xb) {
  int idx = blockIdx.x * 256 + threadIdx.x;   // 524288
  int m = idx >> 7;
  int c8 = idx & 127;
  const float* src = &x[(size_t)m * 1024 + c8 * 8];
  float4 v0 = *(const float4*)&src[0];
  float4 v1 = *(const float4*)&src[4];
  float f[8] = {v0.x, v0.y, v0.z, v0.w, v1.x, v1.y, v1.z, v1.w};
  short8 hv, lv;
#pragma unroll
  for (int c = 0; c < 8; c++) {
    ushort_t h = f2bf(f[c]);
    hv[c] = (short)h;
    lv[c] = (short)f2bf(f[c] - bf2f(h));
  }
  int key = (m >> 1) & 3;
  int phys = (c8 & ~3) * 8 + ((c8 & 3) ^ key) * 8;
  ushort_t* row = xb + (size_t)m * KS2;
  *(short8*)&row[phys] = hv;
  *(short8*)&row[1024 + phys] = lv;
}

// ---------------------------------------------------------------------------
// Kernel 0b: transpose+cast W -> wt[1792][2048] bf16 (hi half only), swizzled.
// ---------------------------------------------------------------------------
__global__ __launch_bounds__(256) void cast_w(
    const float* __restrict__ Wq, const float* __restrict__ Wk,
    const float* __restrict__ Wv, ushort_t* __restrict__ wt) {
  __shared__ float tile[64][65];
  const int n0 = blockIdx.x * 64;
  const int k0 = blockIdx.y * 64;
  const int tid = threadIdx.x;

  const float* Wp; int ldw, noff;
  if (n0 < 1024)      { Wp = Wq; ldw = 1024; noff = n0; }
  else if (n0 < 1280) { Wp = Wk; ldw = 256;  noff = n0 - 1024; }
  else                { Wp = Wv; ldw = 512;  noff = n0 - 1280; }

#pragma unroll
  for (int it = 0; it < 4; it++) {
    int fi = it * 256 + tid;
    int kk = fi >> 4;
    int nc = (fi & 15) * 4;
    float4 v = *(const float4*)&Wp[(size_t)(k0 + kk) * ldw + noff + nc];
    tile[nc + 0][kk] = v.x; tile[nc + 1][kk] = v.y;
    tile[nc + 2][kk] = v.z; tile[nc + 3][kk] = v.w;
  }
  __syncthreads();
  int nn = tid >> 2, seg = tid & 3;
  int n = n0 + nn;
  int key = (n >> 1) & 3;
  ushort_t* row = wt + (size_t)n * KS2;
#pragma unroll
  for (int j = 0; j < 2; j++) {
    short8 hv;
#pragma unroll
    for (int u = 0; u < 8; u++)
      hv[u] = (short)f2bf(tile[nn][seg * 16 + j * 8 + u]);
    int c8 = (k0 >> 3) + seg * 2 + j;
    int phys = (c8 & ~3) * 8 + ((c8 & 3) ^ key) * 8;
    *(short8*)&row[phys] = hv;
  }
}

// ---------------------------------------------------------------------------
// Kernel 0c: cast Wproj[128][1024] -> bf16 B-fragment order.
// ---------------------------------------------------------------------------
__global__ __launch_bounds__(256) void cast_wp(
    const float* __restrict__ Wp, ushort_t* __restrict__ wpf) {
  int idx = blockIdx.x * 256 + threadIdx.x;   // 16384
  int n = idx & 1023;
  int kc = idx >> 10;                          // 0..15 (chunk of 8 k's)
  short8 v;
#pragma unroll
  for (int j = 0; j < 8; j++)
    v[j] = (short)f2bf(Wp[(size_t)(kc * 8 + j) * 1024 + n]);
  size_t off = (((size_t)(n >> 7) * 4 + (kc >> 2)) * 8 + ((n >> 4) & 7)) * 512 +
               ((kc & 3) * 16 + (n & 15)) * 8;
  *(short8*)&wpf[off] = v;
}

// ---------------------------------------------------------------------------
// Kernel 1: bf16-MFMA QKV GEMM.  2-barrier single-buffer K-loop +
// conflict-free swizzled LDS; variable K per column group (64 QK / 32 V).
// ---------------------------------------------------------------------------
__global__ __launch_bounds__(256) void gemm_qkv_mfma(
    const ushort_t* __restrict__ xb, const ushort_t* __restrict__ wt,
    float* __restrict__ qkv) {
  __shared__ ushort_t At[128 * 32];
  __shared__ ushort_t Bt[128 * 32];
  const int tid = threadIdx.x;
  const int wave = tid >> 6, lane = tid & 63;
  const int quad = lane >> 4, l16 = lane & 15;
  const int m0 = blockIdx.y * 128, n0 = blockIdx.x * 128;
  const int wm = (wave & 1) * 64, wn = (wave >> 1) * 64;
  const int physq = (quad ^ ((l16 >> 1) & 3)) * 8;   // de-swizzle read column
  const int ntiles = (n0 >= 1280) ? 32 : 64;

  f32x4 acc[4][4];
#pragma unroll
  for (int i = 0; i < 4; i++)
#pragma unroll
    for (int j = 0; j < 4; j++) acc[i][j] = (f32x4){0.f, 0.f, 0.f, 0.f};

  const int rA = wave * 32 + (lane >> 2);
  const int cA = (lane & 3) * 8;
  const ushort_t* gA = xb + (size_t)(m0 + rA) * KS2 + cA;
  const ushort_t* gB = wt + (size_t)(n0 + rA) * KS2 + cA;
  ushort_t* lA0 = At + (size_t)(wave * 32) * 32;
  ushort_t* lA1 = At + (size_t)(wave * 32 + 16) * 32;
  ushort_t* lB0 = Bt + (size_t)(wave * 32) * 32;
  ushort_t* lB1 = Bt + (size_t)(wave * 32 + 16) * 32;

  for (int kt = 0; kt < ntiles; kt++) {
    const int ca = kt * 32;
    const int cb = (kt < 32 ? kt : kt - 32) * 32;
    __syncthreads();
    GLD_LDS16(gA + ca, lA0);
    GLD_LDS16(gA + ca + 16 * KS2, lA1);
    GLD_LDS16(gB + cb, lB0);
    GLD_LDS16(gB + cb + 16 * KS2, lB1);
    __syncthreads();

    short8 af[4], bf[4];
#pragma unroll
    for (int i = 0; i < 4; i++)
      af[i] = *(const short8*)&At[(wm + 16 * i + l16) * 32 + physq];
#pragma unroll
    for (int j = 0; j < 4; j++)
      bf[j] = *(const short8*)&Bt[(wn + 16 * j + l16) * 32 + physq];
#pragma unroll
    for (int i = 0; i < 4; i++)
#pragma unroll
      for (int j = 0; j < 4; j++)
        acc[i][j] = __builtin_amdgcn_mfma_f32_16x16x32_bf16(
            af[i], bf[j], acc[i][j], 0, 0, 0);
  }

#pragma unroll
  for (int i = 0; i < 4; i++) {
    int m = m0 + wm + 16 * i + quad * 4;
#pragma unroll
    for (int j = 0; j < 4; j++) {
      int n = n0 + wn + 16 * j + l16;
#pragma unroll
      for (int r = 0; r < 4; r++)
        qkv[(size_t)(m + r) * NQKV + n] = acc[i][j][r];
    }
  }
}

// ---------------------------------------------------------------------------
// Kernel 2: RoPE + qk-norm -> unit-norm bf16 q,k in MFMA-fragment layouts.
// ---------------------------------------------------------------------------
__global__ __launch_bounds__(256) void rope_norm(
    const float* __restrict__ qkv,
    ushort_t* __restrict__ qf, ushort_t* __restrict__ kf) {
  const int NQ = B_ * T_ * H_;
  int vec = blockIdx.x * 4 + (threadIdx.x >> 6);
  int d = threadIdx.x & 63;

  size_t src; int t, b, isq; ushort_t* dstbase;
  if (vec < NQ) {
    int h = vec % H_; int bt = vec / H_;
    t = bt % T_; b = bt / T_;
    src = (size_t)bt * NQKV + h * 64 + d;
    dstbase = qf + (size_t)(b * 16 + h) * 131072;
    isq = 1;
  } else {
    int vk = vec - NQ;
    int g = vk % G_; int bt = vk / G_;
    t = bt % T_; b = bt / T_;
    src = (size_t)bt * NQKV + 1024 + g * 64 + d;
    dstbase = kf + (size_t)(b * 4 + g) * 131072;
    isq = 0;
  }
  float val = qkv[src];
  int i = d & 31;
  float inv = exp2f(-(float)i * 0.4152410118074239f);  // log2(10000)/32
  float ang = (float)t * inv;
  float sn, cs;
  __sincosf(ang, &sn, &cs);
  float partner = __shfl(val, d ^ 32, 64);
  float r = (d < 32) ? (val * cs - partner * sn) : (val * cs + partner * sn);
  float ss = r * r;
#pragma unroll
  for (int off = 32; off; off >>= 1) ss += __shfl_xor(ss, off, 64);
  r *= 1.0f / (sqrtf(ss) + 1e-6f);

  int kt = t >> 6, tt = t & 63;
  int l16v = tt & 15;
  int ks = d >> 5, quad = (d >> 3) & 3, j = d & 7;
  size_t off2;
  if (isq) {
    int wavei = tt >> 4;
    off2 = ((size_t)(kt * 8 + wavei * 2 + ks) * 4 + quad) * 128 + l16v * 8 + j;
  } else {
    int nt = tt >> 4;
    off2 = ((size_t)(kt * 8 + ks * 4 + nt) * 4 + quad) * 128 + l16v * 8 + j;
  }
  dstbase[off2] = f2bf(r);
}

// ---------------------------------------------------------------------------
// Kernel 2b: V scatter + bf16 cast into PV B-fragment layout.
// ---------------------------------------------------------------------------
__global__ __launch_bounds__(256) void vscatter(
    const float* __restrict__ qkv, ushort_t* __restrict__ vf) {
  int idx = blockIdx.x * 256 + threadIdx.x;   // 2,097,152
  int dv = idx & 127;
  int t = (idx >> 7) & 2047;
  int g = (idx >> 18) & 3;
  int b = idx >> 20;
  size_t src = (size_t)(b * T_ + t) * NQKV + 1280 + g * 128 + dv;
  float v = qkv[src];
  int kt = t >> 6, ks = (t >> 5) & 1, quad = (t >> 3) & 3, j = t & 7;
  int nv = dv >> 4, l16v = dv & 15;
  size_t off = ((size_t)(kt * 16 + ks * 8 + nv) * 4 + quad) * 128 + l16v * 8 + j;
  vf[(size_t)(b * 4 + g) * 262144 + off] = f2bf(v);
}

// ---------------------------------------------------------------------------
// Kernel 3: bf16-MFMA causal flash attention, fixed-max softmax (m = gsc).
// Barrier-free + DIAGONAL-PAIRED for load balance: block p handles Q-tiles
// tA=p and tB=31-p (total work = 33 iters for every block). Each wave owns
// 16 rows of each tile, shares one K/V fragment load per iter; A-side MFMAs
// run under a wave-uniform kt<=tA branch.
// ---------------------------------------------------------------------------
__global__ __launch_bounds__(256, 2) void attn(
    const ushort_t* __restrict__ qf, const ushort_t* __restrict__ kf,
    const ushort_t* __restrict__ vf, const float* __restrict__ lobo,
    const float* __restrict__ qknf, float* __restrict__ y) {
  const int f = blockIdx.x;            // 512 blocks
  const int b = f >> 8;
  const int h = (f >> 4) & 15;
  const int p = f & 15;
  const int tA = p, tB = 31 - p;
  const int g = h >> 2;

  __shared__ ushort_t Ps[4 * 2176];    // per-wave 2 sets x 16 rows x 68

  const int tid = threadIdx.x;
  const int wave = tid >> 6, lane = tid & 63;
  const int quad = lane >> 4, l16 = lane & 15;
  ushort_t* PsW = &Ps[wave * 2176];

  short8 bones;
  {
    short bv = (l16 == 0) ? (short)0x3F80 : (short)0;
#pragma unroll
    for (int j = 0; j < 8; j++) bones[j] = bv;
  }

  const ushort_t* qbase = qf + (size_t)(b * 16 + h) * 131072 + lane * 8;
  short8 aqA0 = *(const short8*)&qbase[(size_t)(tA * 8 + wave * 2 + 0) * 512];
  short8 aqA1 = *(const short8*)&qbase[(size_t)(tA * 8 + wave * 2 + 1) * 512];
  short8 aqB0 = *(const short8*)&qbase[(size_t)(tB * 8 + wave * 2 + 0) * 512];
  short8 aqB1 = *(const short8*)&qbase[(size_t)(tB * 8 + wave * 2 + 1) * 512];

  f32x4 oA[9], oB[9];
#pragma unroll
  for (int nv = 0; nv < 9; nv++) {
    oA[nv] = (f32x4){0.f, 0.f, 0.f, 0.f};
    oB[nv] = (f32x4){0.f, 0.f, 0.f, 0.f};
  }

  const float gsc = qknf[0];
  const float sinkp = __expf(lobo[h] - gsc);

  const int rowA = tA * 64 + wave * 16 + quad * 4;   // +r
  const int rowB = tB * 64 + wave * 16 + quad * 4;

  const ushort_t* kt0 = kf + (size_t)(b * 4 + g) * 131072 + lane * 8;
  const ushort_t* vt0 = vf + (size_t)(b * 4 + g) * 262144 + lane * 8;

  for (int kt = 0; kt <= tB; kt++) {
    const ushort_t* kg = kt0 + (size_t)kt * 4096;
    const ushort_t* vg = vt0 + (size_t)kt * 8192;
    short8 kfr[8];
#pragma unroll
    for (int u = 0; u < 8; u++) kfr[u] = *(const short8*)&kg[u * 512];
    short8 vfr[16];
#pragma unroll
    for (int u = 0; u < 16; u++) vfr[u] = *(const short8*)&vg[u * 512];

    const int keyb = kt * 64 + l16;
    const bool doA = (kt <= tA);   // wave-uniform

    // ---- B tile (always) ----
    {
      f32x4 s[4];
#pragma unroll
      for (int nt = 0; nt < 4; nt++) s[nt] = (f32x4){0.f, 0.f, 0.f, 0.f};
#pragma unroll
      for (int nt = 0; nt < 4; nt++)
        s[nt] = __builtin_amdgcn_mfma_f32_16x16x32_bf16(aqB0, kfr[nt], s[nt], 0, 0, 0);
#pragma unroll
      for (int nt = 0; nt < 4; nt++)
        s[nt] = __builtin_amdgcn_mfma_f32_16x16x32_bf16(aqB1, kfr[4 + nt], s[nt], 0, 0, 0);
#pragma unroll
      for (int nt = 0; nt < 4; nt++) {
        int key = keyb + nt * 16;
#pragma unroll
        for (int r = 0; r < 4; r++) {
          float pv = (key <= rowB + r) ? __expf((s[nt][r] - 1.0f) * gsc) : 0.f;
          PsW[1088 + (quad * 4 + r) * 68 + nt * 16 + l16] = f2bf(pv);
        }
      }
      short8 ap0 = *(const short8*)&PsW[1088 + l16 * 68 + quad * 8];
      short8 ap1 = *(const short8*)&PsW[1088 + l16 * 68 + 32 + quad * 8];
#pragma unroll
      for (int nv = 0; nv < 8; nv++)
        oB[nv] = __builtin_amdgcn_mfma_f32_16x16x32_bf16(ap0, vfr[nv], oB[nv], 0, 0, 0);
      oB[8] = __builtin_amdgcn_mfma_f32_16x16x32_bf16(ap0, bones, oB[8], 0, 0, 0);
      oB[8] = __builtin_amdgcn_mfma_f32_16x16x32_bf16(ap1, bones, oB[8], 0, 0, 0);
#pragma unroll
      for (int nv = 0; nv < 8; nv++)
        oB[nv] = __builtin_amdgcn_mfma_f32_16x16x32_bf16(ap1, vfr[8 + nv], oB[nv], 0, 0, 0);
    }

    // ---- A tile (while kt <= tA) ----
    if (doA) {
      f32x4 s[4];
#pragma unroll
      for (int nt = 0; nt < 4; nt++) s[nt] = (f32x4){0.f, 0.f, 0.f, 0.f};
#pragma unroll
      for (int nt = 0; nt < 4; nt++)
        s[nt] = __builtin_amdgcn_mfma_f32_16x16x32_bf16(aqA0, kfr[nt], s[nt], 0, 0, 0);
#pragma unroll
      for (int nt = 0; nt < 4; nt++)
        s[nt] = __builtin_amdgcn_mfma_f32_16x16x32_bf16(aqA1, kfr[4 + nt], s[nt], 0, 0, 0);
#pragma unroll
      for (int nt = 0; nt < 4; nt++) {
        int key = keyb + nt * 16;
#pragma unroll
        for (int r = 0; r < 4; r++) {
          float pv = (key <= rowA + r) ? __expf((s[nt][r] - 1.0f) * gsc) : 0.f;
          PsW[(quad * 4 + r) * 68 + nt * 16 + l16] = f2bf(pv);
        }
      }
      short8 ap0 = *(const short8*)&PsW[l16 * 68 + quad * 8];
      short8 ap1 = *(const short8*)&PsW[l16 * 68 + 32 + quad * 8];
#pragma unroll
      for (int nv = 0; nv < 8; nv++)
        oA[nv] = __builtin_amdgcn_mfma_f32_16x16x32_bf16(ap0, vfr[nv], oA[nv], 0, 0, 0);
      oA[8] = __builtin_amdgcn_mfma_f32_16x16x32_bf16(ap0, bones, oA[8], 0, 0, 0);
      oA[8] = __builtin_amdgcn_mfma_f32_16x16x32_bf16(ap1, bones, oA[8], 0, 0, 0);
#pragma unroll
      for (int nv = 0; nv < 8; nv++)
        oA[nv] = __builtin_amdgcn_mfma_f32_16x16x32_bf16(ap1, vfr[8 + nv], oA[nv], 0, 0, 0);
    }
  }

  // epilogue: l = sink + mfma row-sum (col 0 of o[8]); normalize; head-sum
#pragma unroll
  for (int r = 0; r < 4; r++) {
    float lmA = __shfl(oA[8][r], lane & 48, 64);
    float lmB = __shfl(oB[8][r], lane & 48, 64);
    float invlA = 1.0f / (lmA + sinkp);
    float invlB = 1.0f / (lmB + sinkp);
    size_t gRowA = (size_t)b * T_ + rowA + r;
    size_t gRowB = (size_t)b * T_ + rowB + r;
#pragma unroll
    for (int nv = 0; nv < 8; nv++) {
      atomicAdd(&y[gRowA * 128 + nv * 16 + l16], oA[nv][r] * invlA);
      atomicAdd(&y[gRowB * 128 + nv * 16 + l16], oB[nv][r] * invlB);
    }
  }
}

// ---------------------------------------------------------------------------
// Kernel 4: out = y[4096][128] @ Wproj[128][1024] via bf16 MFMA.
// ---------------------------------------------------------------------------
__global__ __launch_bounds__(256) void out_proj(
    const float* __restrict__ y, const ushort_t* __restrict__ wpf,
    float* __restrict__ out) {
  __shared__ ushort_t yl[128 * 136];
  const int tid = threadIdx.x;
  const int wave = tid >> 6, lane = tid & 63;
  const int quad = lane >> 4, l16 = lane & 15;
  const int n0 = blockIdx.x * 128, m0 = blockIdx.y * 128;
  const int wm = (wave & 1) * 64, wn = (wave >> 1) * 64;

#pragma unroll
  for (int it = 0; it < 8; it++) {
    int p = it * 256 + tid;
    int row = p >> 4, c8 = p & 15;
    const float* src = &y[(size_t)(m0 + row) * 128 + c8 * 8];
    float4 v0 = *(const float4*)&src[0];
    float4 v1 = *(const float4*)&src[4];
    float fv[8] = {v0.x, v0.y, v0.z, v0.w, v1.x, v1.y, v1.z, v1.w};
    short8 hv;
#pragma unroll
    for (int c = 0; c < 8; c++) hv[c] = (short)f2bf(fv[c]);
    *(short8*)&yl[row * 136 + c8 * 8] = hv;
  }
  __syncthreads();

  f32x4 acc[4][4];
#pragma unroll
  for (int i = 0; i < 4; i++)
#pragma unroll
    for (int j = 0; j < 4; j++) acc[i][j] = (f32x4){0.f, 0.f, 0.f, 0.f};

#pragma unroll
  for (int ks = 0; ks < 4; ks++) {
    short8 af[4], bfr[4];
#pragma unroll
    for (int i = 0; i < 4; i++)
      af[i] = *(const short8*)&yl[(wm + 16 * i + l16) * 136 + (ks * 4 + quad) * 8];
    const ushort_t* wb = wpf + (((size_t)(n0 >> 7) * 4 + ks) * 8) * 512;
#pragma unroll
    for (int j = 0; j < 4; j++)
      bfr[j] = *(const short8*)&wb[((size_t)((wn >> 4) + j)) * 512 + lane * 8];
#pragma unroll
    for (int i = 0; i < 4; i++)
#pragma unroll
      for (int j = 0; j < 4; j++)
        acc[i][j] = __builtin_amdgcn_mfma_f32_16x16x32_bf16(
            af[i], bfr[j], acc[i][j], 0, 0, 0);
  }

#pragma unroll
  for (int i = 0; i < 4; i++) {
    int m = m0 + wm + 16 * i + quad * 4;
#pragma unroll
    for (int j = 0; j < 4; j++) {
      int n = n0 + wn + 16 * j + l16;
#pragma unroll
      for (int r = 0; r < 4; r++)
        out[(size_t)(m + r) * 1024 + n] = acc[i][j][r];
    }
  }
}

// ---------------------------------------------------------------------------
extern "C" void kernel_launch(void* const* d_in, const int* in_sizes, int n_in,
                              void* d_out, int out_size, void* d_ws, size_t ws_size,
                              hipStream_t stream) {
  const float* x     = (const float*)d_in[0];
  const float* Wq    = (const float*)d_in[2];
  const float* Wk    = (const float*)d_in[3];
  const float* Wv    = (const float*)d_in[4];
  const float* Wproj = (const float*)d_in[5];
  const float* lobo  = (const float*)d_in[6];
  const float* qknf  = (const float*)d_in[7];
  float* out = (float*)d_out;

  // ws: [qkv f32 29.4MB | xb 16.8MB | wt 7.3MB | wpf 0.25MB]; qf/kf/vf/y alias xb.
  float* qkv = (float*)d_ws;                                    // 7,340,032 f32
  ushort_t* xb = (ushort_t*)(qkv + (size_t)B_ * T_ * NQKV);     // 8,388,608 bf16
  ushort_t* wt = xb + (size_t)B_ * T_ * KS2;                    // 3,670,016 bf16
  ushort_t* wpf = wt + (size_t)NQKV * KS2;                      //   131,072 bf16
  ushort_t* qf = xb;                                            // 4,194,304 bf16
  ushort_t* kf = qf + (size_t)B_ * H_ * T_ * 64;                // 1,048,576 bf16
  ushort_t* vf = kf + (size_t)B_ * G_ * T_ * 64;                // 2,097,152 bf16
  float* y = (float*)(vf + (size_t)B_ * G_ * T_ * 128);         //   524,288 f32

  cast_x<<<(B_ * T_ * 128) / 256, 256, 0, stream>>>(x, xb);
  dim3 gw(NQKV / 64, C_ / 64);
  cast_w<<<gw, 256, 0, stream>>>(Wq, Wk, Wv, wt);
  cast_wp<<<64, 256, 0, stream>>>(Wproj, wpf);

  dim3 gg(NQKV / 128, (B_ * T_) / 128);
  gemm_qkv_mfma<<<gg, 256, 0, stream>>>(xb, wt, qkv);

  int nvec = B_ * T_ * H_ + B_ * T_ * G_;   // 81920
  rope_norm<<<nvec / 4, 256, 0, stream>>>(qkv, qf, kf);

  vscatter<<<(B_ * G_ * T_ * DV_) / 256, 256, 0, stream>>>(qkv, vf);

  (void)hipMemsetAsync(y, 0, (size_t)B_ * T_ * 128 * sizeof(float), stream);

  attn<<<B_ * H_ * 16, 256, 0, stream>>>(qf, kf, vf, lobo, qknf, y);

  dim3 go(8, 32);
  out_proj<<<go, 256, 0, stream>>>(y, wpf, out);
}